// Round 2
// baseline (81.911 us; speedup 1.0000x reference)
//
#include <hip/hip_runtime.h>
#include <math.h>

#define CIN  32
#define COUT 32
#define HH   80
#define WW   80
#define TH   16           // output rows per block
#define XROWS (TH + 4)    // 20 haloed rows
#define XCOLS (WW + 4)    // 84 haloed cols
#define NTHREADS 320      // 16 rows x 20 col-groups (4 cols each)

__global__ __launch_bounds__(NTHREADS) void semiconv2d_kernel(
    const float* __restrict__ x,     // [B, CIN, H, W]
    const float* __restrict__ w,     // [COUT, CIN, 5, 5]
    const float* __restrict__ bias,  // [COUT]
    float* __restrict__ out)         // [B, COUT, H, W]
{
    __shared__ __align__(16) float xs[XROWS * XCOLS];   // 20*84 = 1680 floats
    __shared__ __align__(16) float wl[CIN * 28];        // 25 taps padded to 28

    const int tid = threadIdx.x;
    const int bh  = blockIdx.x;    // 0..4  (row stripe)
    const int co  = blockIdx.y;    // 0..31
    const int b   = blockIdx.z;    // 0..3
    const int h0  = bh * TH;

    // ---- stage weights for this co, padded to 28 floats per ci ----
    for (int idx = tid; idx < CIN * 28; idx += NTHREADS) {
        int ci = idx / 28, k = idx % 28;
        wl[idx] = (k < 25) ? w[(co * CIN + ci) * 25 + k] : 0.0f;
    }

    const int ty = tid / 20;       // 0..15 output row within stripe
    const int tx = tid % 20;       // 0..19 column group
    const int wc = tx * 4;         // first of 4 output cols

    // ---- precompute x-tile staging offsets (same for every ci) ----
    int lidx[6], goff[6], cnt = 0;
    for (int idx = tid; idx < XROWS * XCOLS; idx += NTHREADS) {
        int r = idx / XCOLS, c = idx % XCOLS;
        int gr = h0 + r - 2, gc = c - 2;
        lidx[cnt] = idx;
        goff[cnt] = (gr >= 0 && gr < HH && gc >= 0 && gc < WW) ? (gr * WW + gc) : -1;
        ++cnt;
    }

    float sum0 = 0.f, sum1 = 0.f, sum2 = 0.f, sum3 = 0.f;

    for (int ci = 0; ci < CIN; ++ci) {
        __syncthreads();
        // ---- stage haloed x tile for this ci ----
        const float* xp = x + ((size_t)(b * CIN + ci)) * (HH * WW);
        for (int i = 0; i < cnt; ++i) {
            float v = -INFINITY;
            if (goff[i] >= 0) v = xp[goff[i]];
            xs[lidx[i]] = v;
        }
        __syncthreads();

        // ---- weights for this ci into registers (7 x b128) ----
        float wr[28];
        const float4* wv = reinterpret_cast<const float4*>(&wl[ci * 28]);
        #pragma unroll
        for (int i = 0; i < 7; ++i) {
            float4 t = wv[i];
            wr[4*i+0] = t.x; wr[4*i+1] = t.y; wr[4*i+2] = t.z; wr[4*i+3] = t.w;
        }

        // ---- 5 rows x 8 cols of x into registers (2 x b128 per row) ----
        float xr[5][8];
        #pragma unroll
        for (int m = 0; m < 5; ++m) {
            const float4* row = reinterpret_cast<const float4*>(&xs[(ty + m) * XCOLS + wc]);
            float4 a = row[0], c4 = row[1];
            xr[m][0] = a.x;  xr[m][1] = a.y;  xr[m][2] = a.z;  xr[m][3] = a.w;
            xr[m][4] = c4.x; xr[m][5] = c4.y; xr[m][6] = c4.z; xr[m][7] = c4.w;
        }

        // ---- 25 taps, 4 outputs ----
        float mx0 = -INFINITY, mx1 = -INFINITY, mx2 = -INFINITY, mx3 = -INFINITY;
        #pragma unroll
        for (int m = 0; m < 5; ++m) {
            #pragma unroll
            for (int n = 0; n < 5; ++n) {
                float wmn = wr[m * 5 + n];
                mx0 = fmaxf(mx0, xr[m][n + 0] + wmn);
                mx1 = fmaxf(mx1, xr[m][n + 1] + wmn);
                mx2 = fmaxf(mx2, xr[m][n + 2] + wmn);
                mx3 = fmaxf(mx3, xr[m][n + 3] + wmn);
            }
        }
        sum0 += mx0; sum1 += mx1; sum2 += mx2; sum3 += mx3;
    }

    const float bco = bias[co];
    float4 r;
    r.x = sum0 + bco; r.y = sum1 + bco; r.z = sum2 + bco; r.w = sum3 + bco;
    float* op = out + (((size_t)b * COUT + co) * HH + (h0 + ty)) * WW + wc;
    *reinterpret_cast<float4*>(op) = r;
}

extern "C" void kernel_launch(void* const* d_in, const int* in_sizes, int n_in,
                              void* d_out, int out_size, void* d_ws, size_t ws_size,
                              hipStream_t stream) {
    const float* x    = (const float*)d_in[0];
    const float* w    = (const float*)d_in[1];
    const float* bias = (const float*)d_in[2];
    float* out        = (float*)d_out;

    dim3 grid(HH / TH, COUT, 4);   // 5 x 32 x 4 = 640 blocks
    dim3 block(NTHREADS);
    semiconv2d_kernel<<<grid, block, 0, stream>>>(x, w, bias, out);
}

// Round 3
// 38.483 us; speedup vs baseline: 2.1285x; 2.1285x over previous
//
#include <hip/hip_runtime.h>
#include <math.h>

#define CIN  32
#define COUT 32
#define BB   4
#define HH   80
#define WW   80
#define HW   (HH * WW)
#define NOUT (BB * COUT * HW)     // 819200
#define TH   16                   // output rows per block
#define XROWS (TH + 4)            // 20
#define XCOLS (WW + 4)            // 84
#define TILE  (XROWS * XCOLS)     // 1680
#define TILEP 1696                // padded (16B-aligned second buffer)
#define NTHREADS 320              // 16 rows x 20 col-groups (4 cols each)

template<int NPARTS>
__global__ __launch_bounds__(NTHREADS, 6) void semiconv_kernel(
    const float* __restrict__ x,     // [B, CIN, H, W]
    const float* __restrict__ w,     // [COUT, CIN, 5, 5]
    const float* __restrict__ bias,  // [COUT]
    float* __restrict__ dst)         // out (NPARTS==1) or partials [NPARTS][B,COUT,H,W]
{
    constexpr int CIP = CIN / NPARTS;
    __shared__ __align__(16) float xs[2][TILEP];
    __shared__ __align__(16) float wl[CIP * 28];

    const int tid = threadIdx.x;
    const int bh  = blockIdx.x;           // 0..4 row stripe
    const int co  = blockIdx.y;           // 0..31
    const int zz  = blockIdx.z;           // b * NPARTS + part
    const int b    = zz / NPARTS;
    const int part = zz % NPARTS;
    const int ci0  = part * CIP;
    const int h0   = bh * TH;

    // stage weights for this (co, ci-range), padded to 28 floats per ci
    for (int idx = tid; idx < CIP * 28; idx += NTHREADS) {
        int ci = idx / 28, k = idx % 28;
        wl[idx] = (k < 25) ? w[((co * CIN) + ci0 + ci) * 25 + k] : 0.0f;
    }

    const int ty = tid / 20;              // 0..15
    const int tx = tid % 20;              // 0..19
    const int wc = tx * 4;

    // staging offsets (same for every ci): 5 guaranteed + 1 conditional
    int goff[6], lidx[6];
    #pragma unroll
    for (int i = 0; i < 6; ++i) {
        int idx = tid + i * NTHREADS;
        int r = idx / XCOLS, c = idx % XCOLS;
        int gr = h0 + r - 2, gc = c - 2;
        lidx[i] = idx;
        goff[i] = (gr >= 0 && gr < HH && gc >= 0 && gc < WW) ? (gr * WW + gc) : -1;
    }
    const bool has6 = (tid < TILE - 5 * NTHREADS);   // tid < 80

    float pre[6];
    auto prefetch = [&](int ci) {
        const float* xp = x + (size_t)(b * CIN + ci) * HW;
        #pragma unroll
        for (int i = 0; i < 5; ++i)
            pre[i] = (goff[i] >= 0) ? xp[goff[i]] : -INFINITY;
        if (has6) pre[5] = (goff[5] >= 0) ? xp[goff[5]] : -INFINITY;
    };

    prefetch(ci0);
    float sum0 = 0.f, sum1 = 0.f, sum2 = 0.f, sum3 = 0.f;
    int buf = 0;

    for (int k = 0; k < CIP; ++k) {
        float* xb = xs[buf];
        #pragma unroll
        for (int i = 0; i < 5; ++i) xb[lidx[i]] = pre[i];
        if (has6) xb[lidx[5]] = pre[5];
        __syncthreads();
        if (k + 1 < CIP) prefetch(ci0 + k + 1);   // overlaps with compute below

        const float* wk = &wl[k * 28];
        float mx0 = -INFINITY, mx1 = -INFINITY, mx2 = -INFINITY, mx3 = -INFINITY;
        #pragma unroll
        for (int m = 0; m < 5; ++m) {
            const float4* rowp = reinterpret_cast<const float4*>(&xb[(ty + m) * XCOLS + wc]);
            float4 a = rowp[0], c4 = rowp[1];
            float x0=a.x, x1=a.y, x2=a.z, x3=a.w, x4=c4.x, x5=c4.y, x6=c4.z, x7=c4.w;
            float w0=wk[m*5+0], w1=wk[m*5+1], w2=wk[m*5+2], w3=wk[m*5+3], w4=wk[m*5+4];

            float t0 = fmaxf(fmaxf(x0 + w0, x1 + w1), x2 + w2);
            t0 = fmaxf(fmaxf(t0, x3 + w3), x4 + w4);
            mx0 = fmaxf(mx0, t0);
            float t1 = fmaxf(fmaxf(x1 + w0, x2 + w1), x3 + w2);
            t1 = fmaxf(fmaxf(t1, x4 + w3), x5 + w4);
            mx1 = fmaxf(mx1, t1);
            float t2 = fmaxf(fmaxf(x2 + w0, x3 + w1), x4 + w2);
            t2 = fmaxf(fmaxf(t2, x5 + w3), x6 + w4);
            mx2 = fmaxf(mx2, t2);
            float t3 = fmaxf(fmaxf(x3 + w0, x4 + w1), x5 + w2);
            t3 = fmaxf(fmaxf(t3, x6 + w3), x7 + w4);
            mx3 = fmaxf(mx3, t3);
        }
        sum0 += mx0; sum1 += mx1; sum2 += mx2; sum3 += mx3;
        buf ^= 1;
    }

    size_t oi = (((size_t)b * COUT + co) * HH + (h0 + ty)) * WW + wc;
    float4 r;
    if (NPARTS == 1) {
        const float bc = bias[co];
        r.x = sum0 + bc; r.y = sum1 + bc; r.z = sum2 + bc; r.w = sum3 + bc;
    } else {
        r.x = sum0; r.y = sum1; r.z = sum2; r.w = sum3;
        oi += (size_t)part * NOUT;
    }
    *reinterpret_cast<float4*>(dst + oi) = r;
}

__global__ __launch_bounds__(256) void reduce2_kernel(
    const float* __restrict__ ws, const float* __restrict__ bias,
    float* __restrict__ out)
{
    int i4 = blockIdx.x * 256 + threadIdx.x;          // 0..204799
    const float4* p0 = reinterpret_cast<const float4*>(ws);
    const float4* p1 = p0 + (NOUT / 4);
    float4 a = p0[i4], c = p1[i4];
    int co = (i4 / (HW / 4)) & (COUT - 1);            // (i4/1600) % 32
    float bc = bias[co];
    float4 r;
    r.x = a.x + c.x + bc; r.y = a.y + c.y + bc;
    r.z = a.z + c.z + bc; r.w = a.w + c.w + bc;
    reinterpret_cast<float4*>(out)[i4] = r;
}

extern "C" void kernel_launch(void* const* d_in, const int* in_sizes, int n_in,
                              void* d_out, int out_size, void* d_ws, size_t ws_size,
                              hipStream_t stream) {
    const float* x    = (const float*)d_in[0];
    const float* w    = (const float*)d_in[1];
    const float* bias = (const float*)d_in[2];
    float* out        = (float*)d_out;

    const size_t need = 2ull * NOUT * sizeof(float);  // 6.55 MB
    if (ws_size >= need) {
        dim3 grid(HH / TH, COUT, BB * 2);             // 5 x 32 x 8 = 1280 blocks
        semiconv_kernel<2><<<grid, NTHREADS, 0, stream>>>(x, w, bias, (float*)d_ws);
        reduce2_kernel<<<NOUT / 4 / 256, 256, 0, stream>>>((const float*)d_ws, bias, out);
    } else {
        dim3 grid(HH / TH, COUT, BB);                 // 640 blocks fallback
        semiconv_kernel<1><<<grid, NTHREADS, 0, stream>>>(x, w, bias, out);
    }
}